// Round 1
// baseline (1311.468 us; speedup 1.0000x reference)
//
#include <hip/hip_runtime.h>

// SoniaLayer: out[r] = tanh(sqrt(sum_c (W[r,c] - x[c])^2))
// W: [2^20, 256] fp32 (1 GiB) — pure HBM-streaming, roofline ~171 us @ 6.3 TB/s.
// One wave per row: 64 lanes x float4 = 1024 B = one row, perfectly coalesced.
// 4 rows unrolled per wave-iteration for memory-level parallelism.

constexpr int COLS = 256;           // input features
constexpr int F4_PER_ROW = COLS / 4; // 64 = one float4 per lane

__global__ __launch_bounds__(256)
void sonia_kernel(const float* __restrict__ inp,
                  const float* __restrict__ w,
                  float* __restrict__ out,
                  int rows) {
    const int lane   = threadIdx.x & 63;
    const int waveId = blockIdx.x * (blockDim.x >> 6) + (threadIdx.x >> 6);
    const int nwaves = gridDim.x * (blockDim.x >> 6);

    // each lane caches its 4 input elements for the whole kernel
    const float4 iv = ((const float4*)inp)[lane];
    const float4* __restrict__ wv4 = (const float4*)w;

    for (int base = waveId * 4; base < rows; base += nwaves * 4) {
        float s[4];
        if (base + 3 < rows) {
            // 4 independent rows: loads issue back-to-back before any waitcnt use
            #pragma unroll
            for (int r = 0; r < 4; ++r) {
                float4 wv = wv4[(size_t)(base + r) * F4_PER_ROW + lane];
                float dx = wv.x - iv.x;
                float dy = wv.y - iv.y;
                float dz = wv.z - iv.z;
                float dw = wv.w - iv.w;
                s[r] = dx * dx + dy * dy + dz * dz + dw * dw;
            }
            // 4 independent butterfly chains — scheduler interleaves them
            #pragma unroll
            for (int r = 0; r < 4; ++r) {
                #pragma unroll
                for (int off = 32; off; off >>= 1)
                    s[r] += __shfl_xor(s[r], off, 64);
            }
            if (lane == 0) {
                float4 o;
                o.x = tanhf(sqrtf(s[0]));
                o.y = tanhf(sqrtf(s[1]));
                o.z = tanhf(sqrtf(s[2]));
                o.w = tanhf(sqrtf(s[3]));
                *(float4*)(out + base) = o;   // base % 4 == 0 -> 16B aligned
            }
        } else {
            // defensive tail (unused for rows = 2^20)
            for (int r = 0; r < 4 && base + r < rows; ++r) {
                float4 wv = wv4[(size_t)(base + r) * F4_PER_ROW + lane];
                float dx = wv.x - iv.x;
                float dy = wv.y - iv.y;
                float dz = wv.z - iv.z;
                float dw = wv.w - iv.w;
                float sv = dx * dx + dy * dy + dz * dz + dw * dw;
                #pragma unroll
                for (int off = 32; off; off >>= 1)
                    sv += __shfl_xor(sv, off, 64);
                if (lane == 0) out[base + r] = tanhf(sqrtf(sv));
            }
        }
    }
}

extern "C" void kernel_launch(void* const* d_in, const int* in_sizes, int n_in,
                              void* d_out, int out_size, void* d_ws, size_t ws_size,
                              hipStream_t stream) {
    const float* inp = (const float*)d_in[0];   // [1, 256] fp32
    const float* w   = (const float*)d_in[1];   // [2^20, 256] fp32
    float* out       = (float*)d_out;           // [2^20] fp32

    const int rows = in_sizes[1] / COLS;        // 1048576

    // 1024 blocks x 4 waves = 4096 waves, 4 blocks/CU, 64 x 4-row iters per wave
    dim3 grid(1024), block(256);
    sonia_kernel<<<grid, block, 0, stream>>>(inp, w, out, rows);
}